// Round 5
// baseline (100.678 us; speedup 1.0000x reference)
//
#include <hip/hip_runtime.h>

#define NFULL 8192
#define BATCH 4
#define NPTS (NFULL * BATCH)             // 32768 points total
#define TT 256                           // square tile side
#define NT (NFULL / TT)                  // 32 tiles per dim
#define JOBS_PER_B (NT * (NT + 1) / 2)   // 528 triangular tile pairs
#define TOTAL_JOBS (BATCH * JOBS_PER_B)  // 2112
#define IR 4                             // i-points per lane (64*4 = 256 = TT)
#define JW 64                            // j-points per wave (4 waves * 64 = TT)
#define LAMBDA 0.001

// ws layout: float4 pts | float w | float partials | uint counter
#define WS_PTS_OFF   0
#define WS_W_OFF     (NPTS * 16)
#define WS_PART_OFF  (WS_W_OFF + NPTS * 4)
#define WS_CNT_OFF   (WS_PART_OFF + TOTAL_JOBS * 4)

// ---- prep: per-point derived values + zero the completion counter -------
__global__ __launch_bounds__(256)
void KUNi_prep(const float* __restrict__ inputs,
               const float* __restrict__ coords,
               float4* __restrict__ pts,
               float* __restrict__ wts,
               unsigned int* __restrict__ cnt) {
    const int idx = blockIdx.x * 256 + threadIdx.x;    // 0..NPTS-1
    if (idx == 0) *cnt = 0u;                           // stream-ordered before dpp
    const int b = idx >> 13;                           // /8192
    const int n = idx & (NFULL - 1);
    const float* cp = coords + (size_t)idx * 3;
    const float x = cp[0], y = cp[1], z = cp[2];
    const float sq = fmaf(x, x, fmaf(y, y, z * z));
    const float a0 = inputs[(size_t)b * 2 * NFULL + n];
    const float a1 = inputs[(size_t)b * 2 * NFULL + NFULL + n];
    const float w = 1.0f / (1.0f + __expf(a0 - a1));   // softmax(C=2)[1]
    pts[idx] = make_float4(x, y, z, sq);
    wts[idx] = w;
}

__device__ __forceinline__ int tri_off(int t) {        // row start of row t
    return t * (2 * NT + 1 - t) / 2;
}

__global__ __launch_bounds__(256)
void KUNi_dpp_kernel(const float4* __restrict__ pts,
                     const float* __restrict__ wts,
                     float* __restrict__ partials,
                     unsigned int* __restrict__ cnt,
                     float* __restrict__ out) {
    __shared__ float4 sj[TT];            // {-2x, -2y, -2z, sq} of j-tile
    __shared__ float swt[TT];
    __shared__ float sred[4];
    __shared__ bool last;

    const int tid = threadIdx.x;         // 0..255
    const int lane = tid & 63;
    const int wv = tid >> 6;             // wave 0..3
    const int bid = blockIdx.x;          // 0..2111
    const int b = bid / JOBS_PER_B;
    const int p = bid - b * JOBS_PER_B;

    // closed-form triangular decode (ti <= tj), float sqrt + exact fixup
    const float q = (float)(2 * NT + 1); // 65
    int ti = (int)floorf((q - sqrtf(fmaf(-8.0f, (float)p, q * q))) * 0.5f);
    if (p < tri_off(ti)) --ti;
    else if (p >= tri_off(ti + 1)) ++ti;
    const int tj = ti + (p - tri_off(ti));
    const int base = b * NFULL;

    // ---- stage j-tile into LDS with -2 prescale -------------------------
    {
        const float4 jp = pts[base + tj * TT + tid];
        sj[tid] = make_float4(-2.0f * jp.x, -2.0f * jp.y, -2.0f * jp.z, jp.w);
        swt[tid] = wts[base + tj * TT + tid];
    }

    // ---- each lane owns IR i-points in registers (same set every wave) --
    float4 ip[IR]; float iw[IR], acc[IR];
#pragma unroll
    for (int k = 0; k < IR; ++k) {
        ip[k] = pts[base + ti * TT + lane + k * 64];
        iw[k] = wts[base + ti * TT + lane + k * 64];
        acc[k] = 0.0f;
    }

    __syncthreads();

    // ---- each wave: its own 64-j chunk against all 256 i's --------------
    const int j0 = wv * JW;
#pragma unroll 4
    for (int jj = j0; jj < j0 + JW; ++jj) {
        const float4 jv = sj[jj];        // ds_read_b128, uniform broadcast
        const float jw = swt[jj];
#pragma unroll
        for (int k = 0; k < IR; ++k) {
            float t = ip[k].w + jv.w;                  // sq_i + sq_j
            t = fmaf(jv.x, ip[k].x, t);                // -2 x_i x_j
            t = fmaf(jv.y, ip[k].y, t);
            t = fmaf(jv.z, ip[k].z, t);
            t = fmaxf(t, 0.0f);
            float s = __builtin_amdgcn_sqrtf(t);       // v_sqrt_f32
            acc[k] = fmaf(s, jw, acc[k]);              // fold w_j; w_i later
        }
    }

    // ---- fold w_i, weight off-diagonal tiles by 2 (symmetry) ------------
    float v = 0.0f;
#pragma unroll
    for (int k = 0; k < IR; ++k) v = fmaf(iw[k], acc[k], v);
    if (ti != tj) v *= 2.0f;

    // ---- wave butterfly, cross-wave via LDS, one store per block --------
#pragma unroll
    for (int off = 32; off > 0; off >>= 1) v += __shfl_xor(v, off, 64);
    if (lane == 0) sred[wv] = v;
    __syncthreads();
    if (tid == 0) {
        partials[bid] = sred[0] + sred[1] + sred[2] + sred[3];
        __threadfence();                               // make partial visible
        const unsigned int old = atomicAdd(cnt, 1u);
        last = (old == TOTAL_JOBS - 1u);
    }
    __syncthreads();

    // ---- last finished block reduces all partials and writes the output -
    if (last) {
        __threadfence();                               // acquire partials
        double s = 0.0;
        for (int i = tid; i < TOTAL_JOBS; i += 256) s += (double)partials[i];
#pragma unroll
        for (int off = 32; off > 0; off >>= 1) s += __shfl_xor(s, off, 64);
        __shared__ double sd[4];
        if (lane == 0) sd[wv] = s;
        __syncthreads();
        if (tid == 0) {
            const double scale =
                LAMBDA / ((double)BATCH * (double)NFULL * (double)NFULL);
            out[0] = (float)((sd[0] + sd[1] + sd[2] + sd[3]) * scale);
        }
    }
}

extern "C" void kernel_launch(void* const* d_in, const int* in_sizes, int n_in,
                              void* d_out, int out_size, void* d_ws, size_t ws_size,
                              hipStream_t stream) {
    const float* inputs = (const float*)d_in[0];   // (4, 2, 8192) f32
    const float* coords = (const float*)d_in[1];   // (4, 8192, 3) f32
    float* out = (float*)d_out;                    // scalar f32
    char* ws = (char*)d_ws;
    float4* pts = (float4*)(ws + WS_PTS_OFF);
    float* wts = (float*)(ws + WS_W_OFF);
    float* partials = (float*)(ws + WS_PART_OFF);
    unsigned int* cnt = (unsigned int*)(ws + WS_CNT_OFF);

    KUNi_prep<<<NPTS / 256, 256, 0, stream>>>(inputs, coords, pts, wts, cnt);
    KUNi_dpp_kernel<<<TOTAL_JOBS, 256, 0, stream>>>(pts, wts, partials, cnt, out);
}

// Round 6
// 85.784 us; speedup vs baseline: 1.1736x; 1.1736x over previous
//
#include <hip/hip_runtime.h>

#define NFULL 8192
#define BATCH 4
#define NPTS (NFULL * BATCH)             // 32768 points total
#define TT 256                           // square tile side
#define NT (NFULL / TT)                  // 32 tiles per dim
#define JOBS_PER_B (NT * (NT + 1) / 2)   // 528 triangular tile pairs
#define TOTAL_JOBS (BATCH * JOBS_PER_B)  // 2112
#define IR 4                             // i-points per lane (64*4 = 256 = TT)
#define IR2 (IR / 2)                     // f32x2 pairs per lane
#define JW 64                            // j-points per wave (4 waves * 64 = TT)
#define LAMBDA 0.001

typedef float f32x2 __attribute__((ext_vector_type(2)));

// ws layout: float4 pts | float w | float partials
#define WS_PTS_OFF   0
#define WS_W_OFF     (NPTS * 16)
#define WS_PART_OFF  (WS_W_OFF + NPTS * 4)

// ---- prep: materialize per-point derived values once --------------------
__global__ __launch_bounds__(256)
void KUNi_prep(const float* __restrict__ inputs,
               const float* __restrict__ coords,
               float4* __restrict__ pts,
               float* __restrict__ wts) {
    const int idx = blockIdx.x * 256 + threadIdx.x;    // 0..NPTS-1
    const int b = idx >> 13;                           // /8192
    const int n = idx & (NFULL - 1);
    const float* cp = coords + (size_t)idx * 3;
    const float x = cp[0], y = cp[1], z = cp[2];
    const float sq = fmaf(x, x, fmaf(y, y, z * z));
    const float a0 = inputs[(size_t)b * 2 * NFULL + n];
    const float a1 = inputs[(size_t)b * 2 * NFULL + NFULL + n];
    const float w = 1.0f / (1.0f + __expf(a0 - a1));   // softmax(C=2)[1]
    pts[idx] = make_float4(x, y, z, sq);
    wts[idx] = w;
}

__global__ void KUNi_finalize(const float* __restrict__ partials,
                              float* __restrict__ out) {
    const int tid = threadIdx.x;          // 256
    const int lane = tid & 63, wv = tid >> 6;
    double s = 0.0;
    for (int i = tid; i < TOTAL_JOBS; i += 256) s += (double)partials[i];
#pragma unroll
    for (int off = 32; off > 0; off >>= 1) s += __shfl_xor(s, off, 64);
    __shared__ double sd[4];
    if (lane == 0) sd[wv] = s;
    __syncthreads();
    if (tid == 0) {
        const double scale = LAMBDA / ((double)BATCH * (double)NFULL * (double)NFULL);
        out[0] = (float)((sd[0] + sd[1] + sd[2] + sd[3]) * scale);
    }
}

__device__ __forceinline__ int tri_off(int t) {        // row start of row t
    return t * (2 * NT + 1 - t) / 2;
}

__global__ __launch_bounds__(256)
void KUNi_dpp_kernel(const float4* __restrict__ pts,
                     const float* __restrict__ wts,
                     float* __restrict__ partials) {
    __shared__ float4 sj[TT];            // {-2x, -2y, -2z, sq} of j-tile
    __shared__ float swt[TT];
    __shared__ float sred[4];

    const int tid = threadIdx.x;         // 0..255
    const int lane = tid & 63;
    const int wv = tid >> 6;             // wave 0..3
    const int bid = blockIdx.x;          // 0..2111
    const int b = bid / JOBS_PER_B;
    const int p = bid - b * JOBS_PER_B;

    // closed-form triangular decode (ti <= tj), float sqrt + exact fixup
    const float q = (float)(2 * NT + 1); // 65
    int ti = (int)floorf((q - sqrtf(fmaf(-8.0f, (float)p, q * q))) * 0.5f);
    if (p < tri_off(ti)) --ti;
    else if (p >= tri_off(ti + 1)) ++ti;
    const int tj = ti + (p - tri_off(ti));
    const int base = b * NFULL;

    // ---- stage j-tile into LDS with -2 prescale -------------------------
    {
        const float4 jp = pts[base + tj * TT + tid];
        sj[tid] = make_float4(-2.0f * jp.x, -2.0f * jp.y, -2.0f * jp.z, jp.w);
        swt[tid] = wts[base + tj * TT + tid];
    }

    // ---- each lane owns IR i-points, packed as f32x2 SoA pairs ----------
    f32x2 ix2[IR2], iy2[IR2], iz2[IR2], isq2[IR2], iw2[IR2], acc2[IR2];
#pragma unroll
    for (int k = 0; k < IR2; ++k) {
        const float4 p0 = pts[base + ti * TT + lane + (2 * k) * 64];
        const float4 p1 = pts[base + ti * TT + lane + (2 * k + 1) * 64];
        ix2[k]  = (f32x2){p0.x, p1.x};
        iy2[k]  = (f32x2){p0.y, p1.y};
        iz2[k]  = (f32x2){p0.z, p1.z};
        isq2[k] = (f32x2){p0.w, p1.w};
        iw2[k]  = (f32x2){wts[base + ti * TT + lane + (2 * k) * 64],
                          wts[base + ti * TT + lane + (2 * k + 1) * 64]};
        acc2[k] = (f32x2){0.0f, 0.0f};
    }

    __syncthreads();

    // ---- each wave: its own 64-j chunk against all 256 i's --------------
    const int j0 = wv * JW;
#pragma unroll 4
    for (int jj = j0; jj < j0 + JW; ++jj) {
        const float4 jv = sj[jj];        // ds_read_b128, uniform broadcast
        const float jw = swt[jj];
        const f32x2 jx  = {jv.x, jv.x};
        const f32x2 jy  = {jv.y, jv.y};
        const f32x2 jz  = {jv.z, jv.z};
        const f32x2 jsq = {jv.w, jv.w};
        const f32x2 jw2 = {jw, jw};
#pragma unroll
        for (int k = 0; k < IR2; ++k) {
            f32x2 t = isq2[k] + jsq;                       // v_pk_add_f32
            t = __builtin_elementwise_fma(jx, ix2[k], t);  // v_pk_fma_f32
            t = __builtin_elementwise_fma(jy, iy2[k], t);
            t = __builtin_elementwise_fma(jz, iz2[k], t);
            t = __builtin_elementwise_max(t, (f32x2){0.0f, 0.0f});
            f32x2 s;
            s.x = __builtin_amdgcn_sqrtf(t.x);             // v_sqrt_f32
            s.y = __builtin_amdgcn_sqrtf(t.y);
            acc2[k] = __builtin_elementwise_fma(s, jw2, acc2[k]);
        }
    }

    // ---- fold w_i, weight off-diagonal tiles by 2 (symmetry) ------------
    f32x2 vv = iw2[0] * acc2[0];
#pragma unroll
    for (int k = 1; k < IR2; ++k)
        vv = __builtin_elementwise_fma(iw2[k], acc2[k], vv);
    float v = vv.x + vv.y;
    if (ti != tj) v *= 2.0f;

    // ---- wave butterfly, cross-wave via LDS, one store per block --------
#pragma unroll
    for (int off = 32; off > 0; off >>= 1) v += __shfl_xor(v, off, 64);
    if (lane == 0) sred[wv] = v;
    __syncthreads();
    if (tid == 0) partials[bid] = sred[0] + sred[1] + sred[2] + sred[3];
}

extern "C" void kernel_launch(void* const* d_in, const int* in_sizes, int n_in,
                              void* d_out, int out_size, void* d_ws, size_t ws_size,
                              hipStream_t stream) {
    const float* inputs = (const float*)d_in[0];   // (4, 2, 8192) f32
    const float* coords = (const float*)d_in[1];   // (4, 8192, 3) f32
    float* out = (float*)d_out;                    // scalar f32
    char* ws = (char*)d_ws;
    float4* pts = (float4*)(ws + WS_PTS_OFF);
    float* wts = (float*)(ws + WS_W_OFF);
    float* partials = (float*)(ws + WS_PART_OFF);

    KUNi_prep<<<NPTS / 256, 256, 0, stream>>>(inputs, coords, pts, wts);
    KUNi_dpp_kernel<<<TOTAL_JOBS, 256, 0, stream>>>(pts, wts, partials);
    KUNi_finalize<<<1, 256, 0, stream>>>(partials, out);
}